// Round 2
// baseline (1140.332 us; speedup 1.0000x reference)
//
#include <hip/hip_runtime.h>
#include <hip/hip_bf16.h>
#include <cstdint>

// ---------------------------------------------------------------------------
// DecoderRNN: embed-gather + concat-GEMM (x_proj), 32-step LSTM, vocab GEMM.
// B=64 T=32 E=512 H=1024 V=32000. All heavy GEMMs in bf16 MFMA (16x16x32).
// ---------------------------------------------------------------------------

typedef __bf16 bf16x8 __attribute__((ext_vector_type(8)));
typedef __bf16 bf16x4 __attribute__((ext_vector_type(4)));
typedef float  f32x4  __attribute__((ext_vector_type(4)));

__device__ __forceinline__ void gload_lds16(const void* g, void* l) {
  __builtin_amdgcn_global_load_lds(
      (const __attribute__((address_space(1))) void*)g,
      (__attribute__((address_space(3))) void*)l, 16, 0, 0);
}

__device__ __forceinline__ float sigf(float x) {
  x = fminf(fmaxf(x, -30.f), 30.f);
  return 1.f / (1.f + __expf(-x));
}
__device__ __forceinline__ float tanhf_(float x) {
  x = fminf(fmaxf(x, -15.f), 15.f);
  float e = __expf(2.f * x);
  return (e - 1.f) / (e + 1.f);
}

// ------------------------------ small utility kernels ----------------------

__global__ __launch_bounds__(256) void cast_bf16_kernel(
    const float* __restrict__ s, __bf16* __restrict__ d, long n4) {
  long i = (long)blockIdx.x * 256 + threadIdx.x;
  long stride = (long)gridDim.x * 256;
  for (; i < n4; i += stride) {
    float4 v = ((const float4*)s)[i];
    bf16x4 o = {(__bf16)v.x, (__bf16)v.y, (__bf16)v.z, (__bf16)v.w};
    *(bf16x4*)(d + i * 4) = o;
  }
}

__global__ __launch_bounds__(256) void bias_sum_kernel(
    const float* __restrict__ a, const float* __restrict__ b,
    float* __restrict__ o) {
  int i = blockIdx.x * 256 + threadIdx.x;  // 4096 total
  o[i] = a[i] + b[i];
}

__global__ __launch_bounds__(256) void init_hc_kernel(
    const float* __restrict__ h0, const float* __restrict__ c0,
    __bf16* __restrict__ hbuf, float* __restrict__ c_st) {
  int i = blockIdx.x * 256 + threadIdx.x;  // 65536 total
  hbuf[i] = (__bf16)h0[i];
  c_st[i] = c0[i];
}

// Build A' = [embed_table[inputs[m]] , enc[m/T]] as bf16, rows m=0..2047, K=1024
__global__ __launch_bounds__(256) void gather_xin_kernel(
    const int* __restrict__ inp, const float* __restrict__ emb,
    const float* __restrict__ enc, __bf16* __restrict__ xin) {
  int m = blockIdx.x;          // 0..2047  (m = b*32 + t)
  int tid = threadIdx.x;       // 0..255, 4 cols each
  int idx = inp[m];
  int b = m >> 5;              // T = 32
  int col = tid * 4;
  const float* src = (col < 512) ? emb + (size_t)idx * 512 + col
                                 : enc + (size_t)b * 512 + (col - 512);
  float4 v = *(const float4*)src;
  bf16x4 o = {(__bf16)v.x, (__bf16)v.y, (__bf16)v.z, (__bf16)v.w};
  *(bf16x4*)(xin + (size_t)m * 1024 + col) = o;
}

// ------------------------------ bf16 GEMM (B^T layout) ---------------------
// C[m,n] = sum_k A[m,k]*B[n,k] + colBias[n].  A: MxK bf16, B: NxK bf16.
// 128x128 tile, BK=64, 256 threads (4 waves, 2x2 of 64x64 wave tiles).
__global__ __launch_bounds__(256) void gemm_bt(
    const __bf16* __restrict__ A, const __bf16* __restrict__ B,
    float* __restrict__ C, const float* __restrict__ colBias,
    int M, int N, int K) {
  __shared__ __bf16 As[128][64];
  __shared__ __bf16 Bs[128][64];
  const int tid = threadIdx.x;
  const int w = tid >> 6, l = tid & 63;
  const int m0 = blockIdx.y * 128, n0 = blockIdx.x * 128;
  const int wm = (w >> 1) * 64, wn = (w & 1) * 64;
  const int lr = l >> 3;         // row-in-8 for staging
  const int lc = (l & 7) * 8;    // col (bf16 elems) for staging
  const int fr = l & 15;         // fragment row (m or n within 16-tile)
  const int fk = (l >> 4) * 8;   // fragment k offset
  f32x4 acc[4][4] = {};

  for (int kt = 0; kt < K; kt += 64) {
    __syncthreads();
#pragma unroll
    for (int i = 0; i < 4; ++i) {
      int row = i * 32 + w * 8;  // wave-uniform LDS base row
      gload_lds16(A + (size_t)(m0 + row + lr) * K + kt + lc, &As[row][0]);
      gload_lds16(B + (size_t)(n0 + row + lr) * K + kt + lc, &Bs[row][0]);
    }
    __syncthreads();
#pragma unroll
    for (int ks = 0; ks < 2; ++ks) {
      bf16x8 a[4], b[4];
#pragma unroll
      for (int mi = 0; mi < 4; ++mi)
        a[mi] = *(const bf16x8*)&As[wm + mi * 16 + fr][ks * 32 + fk];
#pragma unroll
      for (int ni = 0; ni < 4; ++ni)
        b[ni] = *(const bf16x8*)&Bs[wn + ni * 16 + fr][ks * 32 + fk];
#pragma unroll
      for (int mi = 0; mi < 4; ++mi)
#pragma unroll
        for (int ni = 0; ni < 4; ++ni)
          acc[mi][ni] = __builtin_amdgcn_mfma_f32_16x16x32_bf16(
              a[mi], b[ni], acc[mi][ni], 0, 0, 0);
    }
  }

  const int col = l & 15, rowb = (l >> 4) * 4;
#pragma unroll
  for (int mi = 0; mi < 4; ++mi)
#pragma unroll
    for (int ni = 0; ni < 4; ++ni) {
      int n = n0 + wn + ni * 16 + col;
      float bias = colBias ? colBias[n] : 0.f;
#pragma unroll
      for (int r = 0; r < 4; ++r) {
        int m = m0 + wm + mi * 16 + rowb + r;
        C[(size_t)m * N + n] = acc[mi][ni][r] + bias;
      }
    }
}

// ------------------------------ fused LSTM step ----------------------------
// z = x_proj[:,t,:] + h @ W_hh^T ; gates; write h (bf16 x2), c, (hn,cn at t=31)
// grid: 64 blocks (16 j's each), 256 threads (4 waves = 4 batch tiles of 16).
__global__ __launch_bounds__(256) void lstm_step(
    const __bf16* __restrict__ hin, const __bf16* __restrict__ Whh,
    const float* __restrict__ xproj, float* __restrict__ c_st,
    __bf16* __restrict__ hout, __bf16* __restrict__ hs,
    float* __restrict__ hn, float* __restrict__ cn, int t) {
  __shared__ __bf16 As[64][64];        // h tile: all 64 batches x 64 k
  __shared__ __bf16 Bs[4][16][64];     // W rows: 4 gates x 16 j x 64 k
  const int tid = threadIdx.x, w = tid >> 6, l = tid & 63;
  const int j0 = blockIdx.x * 16;
  const int lr = l >> 3, lc = (l & 7) * 8;
  const int fr = l & 15, fk = (l >> 4) * 8;
  f32x4 acc[4] = {};

  for (int kt = 0; kt < 1024; kt += 64) {
    __syncthreads();
#pragma unroll
    for (int i = 0; i < 2; ++i) {
      int row = w * 16 + i * 8;                     // 0..63, wave-uniform
      gload_lds16(hin + (size_t)(row + lr) * 1024 + kt + lc, &As[row][0]);
      int frow = row + lr;                          // 0..63
      int gate = frow >> 4, jr = frow & 15;
      gload_lds16(Whh + (size_t)(gate * 1024 + j0 + jr) * 1024 + kt + lc,
                  (__bf16*)Bs + (size_t)row * 64);
    }
    __syncthreads();
#pragma unroll
    for (int ks = 0; ks < 2; ++ks) {
      bf16x8 a = *(const bf16x8*)&As[w * 16 + fr][ks * 32 + fk];
#pragma unroll
      for (int g = 0; g < 4; ++g) {
        bf16x8 b = *(const bf16x8*)&Bs[g][fr][ks * 32 + fk];
        acc[g] = __builtin_amdgcn_mfma_f32_16x16x32_bf16(a, b, acc[g], 0, 0, 0);
      }
    }
  }

  const int col = l & 15, rowb = (l >> 4) * 4;
  const int j = j0 + col;
#pragma unroll
  for (int r = 0; r < 4; ++r) {
    int b = w * 16 + rowb + r;                      // batch index
    size_t xbase = ((size_t)b * 32 + t) * 4096 + j;
    float zi = acc[0][r] + xproj[xbase];
    float zf = acc[1][r] + xproj[xbase + 1024];
    float zg = acc[2][r] + xproj[xbase + 2048];
    float zo = acc[3][r] + xproj[xbase + 3072];
    float ii = sigf(zi), ff = sigf(zf), gg = tanhf_(zg), oo = sigf(zo);
    size_t hc = (size_t)b * 1024 + j;
    float cv = ff * c_st[hc] + ii * gg;
    float hv = oo * tanhf_(cv);
    c_st[hc] = cv;
    __bf16 hb = (__bf16)hv;
    hout[hc] = hb;
    hs[((size_t)b * 32 + t) * 1024 + j] = hb;
    if (t == 31) { hn[hc] = hv; cn[hc] = cv; }
  }
}

// ------------------------------ launch -------------------------------------

extern "C" void kernel_launch(void* const* d_in, const int* in_sizes, int n_in,
                              void* d_out, int out_size, void* d_ws,
                              size_t ws_size, hipStream_t stream) {
  const int*   inp = (const int*)d_in[0];
  const float* enc = (const float*)d_in[1];
  const float* h0  = (const float*)d_in[2];
  const float* c0  = (const float*)d_in[3];
  const float* emb = (const float*)d_in[4];
  const float* Wih = (const float*)d_in[5];
  const float* Whh = (const float*)d_in[6];
  const float* bih = (const float*)d_in[7];
  const float* bhh = (const float*)d_in[8];
  const float* fcW = (const float*)d_in[9];
  const float* fcb = (const float*)d_in[10];

  float* out    = (float*)d_out;
  float* logits = out;                         // 2048 x 32000
  float* hn     = out + 65536000LL;            // 64 x 1024
  float* cn     = hn + 65536;

  char* p = (char*)d_ws;
  __bf16* wih_bf = (__bf16*)p; p += 8388608;      // 4096x1024
  __bf16* whh_bf = (__bf16*)p; p += 8388608;      // 4096x1024
  __bf16* fcw_bf = (__bf16*)p; p += 65536000;     // 32000x1024
  float*  bsum   = (float*)p;  p += 16384;        // 4096
  __bf16* xin    = (__bf16*)p; p += 4194304;      // 2048x1024 (A')
  float*  xproj  = (float*)p;  p += 33554432;     // 2048x4096 f32
  __bf16* hbuf0  = (__bf16*)p; p += 131072;       // 64x1024
  __bf16* hbuf1  = (__bf16*)p; p += 131072;
  float*  c_st   = (float*)p;  p += 262144;       // 64x1024 f32
  __bf16* hs     = (__bf16*)p; p += 4194304;      // 2048x1024

  cast_bf16_kernel<<<1024, 256, 0, stream>>>(Wih, wih_bf, 1048576);
  cast_bf16_kernel<<<1024, 256, 0, stream>>>(Whh, whh_bf, 1048576);
  cast_bf16_kernel<<<2048, 256, 0, stream>>>(fcW, fcw_bf, 8192000);
  bias_sum_kernel<<<16, 256, 0, stream>>>(bih, bhh, bsum);
  init_hc_kernel<<<256, 256, 0, stream>>>(h0, c0, hbuf0, c_st);
  gather_xin_kernel<<<2048, 256, 0, stream>>>(inp, emb, enc, xin);

  // x_proj = A' @ W_ih^T + (b_ih + b_hh):  M=2048 N=4096 K=1024
  gemm_bt<<<dim3(32, 16), 256, 0, stream>>>(xin, wih_bf, xproj, bsum,
                                            2048, 4096, 1024);

  for (int t = 0; t < 32; ++t) {
    const __bf16* hi = (t & 1) ? hbuf1 : hbuf0;
    __bf16*       ho = (t & 1) ? hbuf0 : hbuf1;
    lstm_step<<<64, 256, 0, stream>>>(hi, whh_bf, xproj, c_st, ho, hs, hn, cn, t);
  }

  // logits = hs @ fc_W^T + fc_b:  M=2048 N=32000 K=1024
  gemm_bt<<<dim3(250, 16), 256, 0, stream>>>(hs, fcw_bf, logits, fcb,
                                             2048, 32000, 1024);
}

// Round 3
// 1066.837 us; speedup vs baseline: 1.0689x; 1.0689x over previous
//
#include <hip/hip_runtime.h>
#include <hip/hip_bf16.h>
#include <cstdint>

// ---------------------------------------------------------------------------
// DecoderRNN: embed-gather + concat-GEMM (x_proj), 32-step LSTM, vocab GEMM.
// B=64 T=32 E=512 H=1024 V=32000. All heavy GEMMs in bf16 MFMA (16x16x32).
// R2: XCD-chunk + m-fastest block swizzle on GEMMs (B-panel L2 reuse);
//     LSTM step: W in LDS (swizzled, preloaded once), barrier-free K-loop
//     with A-fragments direct from global.
// ---------------------------------------------------------------------------

typedef __bf16 bf16x8 __attribute__((ext_vector_type(8)));
typedef __bf16 bf16x4 __attribute__((ext_vector_type(4)));
typedef float  f32x4  __attribute__((ext_vector_type(4)));

__device__ __forceinline__ void gload_lds16(const void* g, void* l) {
  __builtin_amdgcn_global_load_lds(
      (const __attribute__((address_space(1))) void*)g,
      (__attribute__((address_space(3))) void*)l, 16, 0, 0);
}

__device__ __forceinline__ float sigf(float x) {
  x = fminf(fmaxf(x, -30.f), 30.f);
  return 1.f / (1.f + __expf(-x));
}
__device__ __forceinline__ float tanhf_(float x) {
  x = fminf(fmaxf(x, -15.f), 15.f);
  float e = __expf(2.f * x);
  return (e - 1.f) / (e + 1.f);
}

// ------------------------------ small utility kernels ----------------------

__global__ __launch_bounds__(256) void cast_bf16_kernel(
    const float* __restrict__ s, __bf16* __restrict__ d, long n4) {
  long i = (long)blockIdx.x * 256 + threadIdx.x;
  long stride = (long)gridDim.x * 256;
  for (; i < n4; i += stride) {
    float4 v = ((const float4*)s)[i];
    bf16x4 o = {(__bf16)v.x, (__bf16)v.y, (__bf16)v.z, (__bf16)v.w};
    *(bf16x4*)(d + i * 4) = o;
  }
}

__global__ __launch_bounds__(256) void bias_sum_kernel(
    const float* __restrict__ a, const float* __restrict__ b,
    float* __restrict__ o) {
  int i = blockIdx.x * 256 + threadIdx.x;  // 4096 total
  o[i] = a[i] + b[i];
}

__global__ __launch_bounds__(256) void init_hc_kernel(
    const float* __restrict__ h0, const float* __restrict__ c0,
    __bf16* __restrict__ hbuf, float* __restrict__ c_st) {
  int i = blockIdx.x * 256 + threadIdx.x;  // 65536 total
  hbuf[i] = (__bf16)h0[i];
  c_st[i] = c0[i];
}

// Build A' = [embed_table[inputs[m]] , enc[m/T]] as bf16, rows m=0..2047, K=1024
__global__ __launch_bounds__(256) void gather_xin_kernel(
    const int* __restrict__ inp, const float* __restrict__ emb,
    const float* __restrict__ enc, __bf16* __restrict__ xin) {
  int m = blockIdx.x;          // 0..2047  (m = b*32 + t)
  int tid = threadIdx.x;       // 0..255, 4 cols each
  int idx = inp[m];
  int b = m >> 5;              // T = 32
  int col = tid * 4;
  const float* src = (col < 512) ? emb + (size_t)idx * 512 + col
                                 : enc + (size_t)b * 512 + (col - 512);
  float4 v = *(const float4*)src;
  bf16x4 o = {(__bf16)v.x, (__bf16)v.y, (__bf16)v.z, (__bf16)v.w};
  *(bf16x4*)(xin + (size_t)m * 1024 + col) = o;
}

// ------------------------------ bf16 GEMM (B^T layout) ---------------------
// C[m,n] = sum_k A[m,k]*B[n,k] + colBias[n].  A: MxK bf16, B: NxK bf16.
// 128x128 tile, BK=64, 256 threads (4 waves, 2x2 of 64x64 wave tiles).
// Grid MUST be (MT=16, NT) with MT*NT % 8 == 0.  Block order: bijective
// XCD-chunk swizzle, m-fastest within chunk -> 16 consecutive blocks on one
// XCD share one B panel (256 KB, L2-resident).
__global__ __launch_bounds__(256) void gemm_bt(
    const __bf16* __restrict__ A, const __bf16* __restrict__ B,
    float* __restrict__ C, const float* __restrict__ colBias,
    int M, int N, int K) {
  __shared__ __bf16 As[128][64];
  __shared__ __bf16 Bs[128][64];
  const int tid = threadIdx.x;
  const int w = tid >> 6, l = tid & 63;
  const int nwg = gridDim.x * gridDim.y;
  const int orig = blockIdx.y * gridDim.x + blockIdx.x;
  const int q = nwg >> 3;                       // nwg divisible by 8
  const int wid = (orig & 7) * q + (orig >> 3); // contiguous chunk per XCD
  const int m0 = (wid & 15) << 7;               // MT = 16 (M = 2048)
  const int n0 = (wid >> 4) << 7;
  const int wm = (w >> 1) * 64, wn = (w & 1) * 64;
  const int lr = l >> 3;         // row-in-8 for staging
  const int lc = (l & 7) * 8;    // col (bf16 elems) for staging
  const int fr = l & 15;         // fragment row (m or n within 16-tile)
  const int fk = (l >> 4) * 8;   // fragment k offset
  f32x4 acc[4][4] = {};

  for (int kt = 0; kt < K; kt += 64) {
    __syncthreads();
#pragma unroll
    for (int i = 0; i < 4; ++i) {
      int row = i * 32 + w * 8;  // wave-uniform LDS base row
      gload_lds16(A + (size_t)(m0 + row + lr) * K + kt + lc, &As[row][0]);
      gload_lds16(B + (size_t)(n0 + row + lr) * K + kt + lc, &Bs[row][0]);
    }
    __syncthreads();
#pragma unroll
    for (int ks = 0; ks < 2; ++ks) {
      bf16x8 a[4], b[4];
#pragma unroll
      for (int mi = 0; mi < 4; ++mi)
        a[mi] = *(const bf16x8*)&As[wm + mi * 16 + fr][ks * 32 + fk];
#pragma unroll
      for (int ni = 0; ni < 4; ++ni)
        b[ni] = *(const bf16x8*)&Bs[wn + ni * 16 + fr][ks * 32 + fk];
#pragma unroll
      for (int mi = 0; mi < 4; ++mi)
#pragma unroll
        for (int ni = 0; ni < 4; ++ni)
          acc[mi][ni] = __builtin_amdgcn_mfma_f32_16x16x32_bf16(
              a[mi], b[ni], acc[mi][ni], 0, 0, 0);
    }
  }

  const int col = l & 15, rowb = (l >> 4) * 4;
#pragma unroll
  for (int mi = 0; mi < 4; ++mi)
#pragma unroll
    for (int ni = 0; ni < 4; ++ni) {
      int n = n0 + wn + ni * 16 + col;
      float bias = colBias ? colBias[n] : 0.f;
#pragma unroll
      for (int r = 0; r < 4; ++r) {
        int m = m0 + wm + mi * 16 + rowb + r;
        C[(size_t)m * N + n] = acc[mi][ni][r] + bias;
      }
    }
}

// ------------------------------ fused LSTM step ----------------------------
// z = x_proj[:,t,:] + h @ W_hh^T ; gates; write h (bf16 x2), c, (hn,cn at t=31)
// grid: 64 blocks (16 j's each), 256 threads (4 waves = 4 batch tiles of 16).
// W-slice (4 gates x 16 j x 1024 k = 128 KB) preloaded into LDS with
// byte ^= (row&7)<<4 swizzle (row stride 2048B would be 16-way conflict).
// K-loop is barrier-free: A fragments stream from global (h is 128 KB, hot).
__global__ __launch_bounds__(256) void lstm_step(
    const __bf16* __restrict__ hin, const __bf16* __restrict__ Whh,
    const float* __restrict__ xproj, float* __restrict__ c_st,
    __bf16* __restrict__ hout, __bf16* __restrict__ hs,
    float* __restrict__ hn, float* __restrict__ cn, int t) {
  __shared__ alignas(16) __bf16 Bsw[4][16][1024];   // 128 KB, swizzled
  const int tid = threadIdx.x, w = tid >> 6, l = tid & 63;
  const int j0 = blockIdx.x * 16;
  const int fr = l & 15;
  const int fk = (l >> 4) * 8;      // k sub-offset (elems)

  // ---- preload W-slice, reg-staged with swizzled ds_write ----
  char* ldsb = (char*)&Bsw[0][0][0];
#pragma unroll
  for (int it = 0; it < 32; ++it) {
    int o = it * 4096 + tid * 16;           // linear byte in 128 KB
    int row = o >> 11;                      // 0..63 = g*16 + jj
    int colb = o & 2047;
    int g = row >> 4, jj = row & 15;
    bf16x8 v = *(const bf16x8*)((const char*)Whh +
                 ((size_t)(g << 10) + j0 + jj) * 2048 + colb);
    *(bf16x8*)(ldsb + (row << 11) + (colb ^ ((row & 7) << 4))) = v;
  }
  __syncthreads();

  // ---- barrier-free K loop: A direct from global, B from swizzled LDS ----
  const __bf16* aptr = hin + (size_t)(w * 16 + fr) * 1024 + fk;
  const int xv = (fr & 7) << 4;             // lane's row-XOR value
  f32x4 acc[4] = {};
#pragma unroll 8
  for (int ks = 0; ks < 32; ++ks) {
    bf16x8 a = *(const bf16x8*)(aptr + ks * 32);
    int cb = ks * 64 + ((l >> 4) << 4);     // byte col within row
#pragma unroll
    for (int g = 0; g < 4; ++g) {
      int rb = ((g << 4) + fr) << 11;       // row byte base
      bf16x8 b = *(const bf16x8*)(ldsb + rb + (cb ^ xv));
      acc[g] = __builtin_amdgcn_mfma_f32_16x16x32_bf16(a, b, acc[g], 0, 0, 0);
    }
  }

  // ---- gates epilogue ----
  const int col = l & 15, rowb = (l >> 4) * 4;
  const int j = j0 + col;
#pragma unroll
  for (int r = 0; r < 4; ++r) {
    int b = w * 16 + rowb + r;                      // batch index
    size_t xbase = ((size_t)b * 32 + t) * 4096 + j;
    float zi = acc[0][r] + xproj[xbase];
    float zf = acc[1][r] + xproj[xbase + 1024];
    float zg = acc[2][r] + xproj[xbase + 2048];
    float zo = acc[3][r] + xproj[xbase + 3072];
    float ii = sigf(zi), ff = sigf(zf), gg = tanhf_(zg), oo = sigf(zo);
    size_t hc = (size_t)b * 1024 + j;
    float cv = ff * c_st[hc] + ii * gg;
    float hv = oo * tanhf_(cv);
    c_st[hc] = cv;
    __bf16 hb = (__bf16)hv;
    hout[hc] = hb;
    hs[((size_t)b * 32 + t) * 1024 + j] = hb;
    if (t == 31) { hn[hc] = hv; cn[hc] = cv; }
  }
}

// ------------------------------ launch -------------------------------------

extern "C" void kernel_launch(void* const* d_in, const int* in_sizes, int n_in,
                              void* d_out, int out_size, void* d_ws,
                              size_t ws_size, hipStream_t stream) {
  const int*   inp = (const int*)d_in[0];
  const float* enc = (const float*)d_in[1];
  const float* h0  = (const float*)d_in[2];
  const float* c0  = (const float*)d_in[3];
  const float* emb = (const float*)d_in[4];
  const float* Wih = (const float*)d_in[5];
  const float* Whh = (const float*)d_in[6];
  const float* bih = (const float*)d_in[7];
  const float* bhh = (const float*)d_in[8];
  const float* fcW = (const float*)d_in[9];
  const float* fcb = (const float*)d_in[10];

  float* out    = (float*)d_out;
  float* logits = out;                         // 2048 x 32000
  float* hn     = out + 65536000LL;            // 64 x 1024
  float* cn     = hn + 65536;

  char* p = (char*)d_ws;
  __bf16* wih_bf = (__bf16*)p; p += 8388608;      // 4096x1024
  __bf16* whh_bf = (__bf16*)p; p += 8388608;      // 4096x1024
  __bf16* fcw_bf = (__bf16*)p; p += 65536000;     // 32000x1024
  float*  bsum   = (float*)p;  p += 16384;        // 4096
  __bf16* xin    = (__bf16*)p; p += 4194304;      // 2048x1024 (A')
  float*  xproj  = (float*)p;  p += 33554432;     // 2048x4096 f32
  __bf16* hbuf0  = (__bf16*)p; p += 131072;       // 64x1024
  __bf16* hbuf1  = (__bf16*)p; p += 131072;
  float*  c_st   = (float*)p;  p += 262144;       // 64x1024 f32
  __bf16* hs     = (__bf16*)p; p += 4194304;      // 2048x1024

  cast_bf16_kernel<<<1024, 256, 0, stream>>>(Wih, wih_bf, 1048576);
  cast_bf16_kernel<<<1024, 256, 0, stream>>>(Whh, whh_bf, 1048576);
  cast_bf16_kernel<<<2048, 256, 0, stream>>>(fcW, fcw_bf, 8192000);
  bias_sum_kernel<<<16, 256, 0, stream>>>(bih, bhh, bsum);
  init_hc_kernel<<<256, 256, 0, stream>>>(h0, c0, hbuf0, c_st);
  gather_xin_kernel<<<2048, 256, 0, stream>>>(inp, emb, enc, xin);

  // x_proj = A' @ W_ih^T + (b_ih + b_hh):  M=2048 N=4096 K=1024
  gemm_bt<<<dim3(16, 32), 256, 0, stream>>>(xin, wih_bf, xproj, bsum,
                                            2048, 4096, 1024);

  for (int t = 0; t < 32; ++t) {
    const __bf16* hi = (t & 1) ? hbuf1 : hbuf0;
    __bf16*       ho = (t & 1) ? hbuf0 : hbuf1;
    lstm_step<<<64, 256, 0, stream>>>(hi, whh_bf, xproj, c_st, ho, hs, hn, cn, t);
  }

  // logits = hs @ fc_W^T + fc_b:  M=2048 N=32000 K=1024
  gemm_bt<<<dim3(16, 250), 256, 0, stream>>>(hs, fcw_bf, logits, fcb,
                                             2048, 32000, 1024);
}